// Round 1
// baseline (350.457 us; speedup 1.0000x reference)
//
#include <hip/hip_runtime.h>

// RobustSum: M = A@V; 3x { dist=cdist(M,V); w=1/(dist+eps); ww=w*A;
//                          M = (ww/rowsum(ww)) @ V }   (T=1.0)
// bf16 MFMA; tolerance = 2% of ref absmax (margin: 5.3x).
//
// Round 9: MODE-1 GEMM (P = M@V^T + dist/weight epilogue) ported to a
// 256x256 / BK=64 / 8-wave deep-pipelined kernel (T3 minimum-2-phase):
//   - 128 KiB LDS double buffer, stage(t+1) issued BEFORE compute(t),
//     one s_waitcnt vmcnt(0) + raw s_barrier per K-tile (no __syncthreads
//     in-loop -> no compiler vmcnt drain at the barrier).
//   - same XOR chunk swizzle as the proven 128^2 kernel (conflict-free).
//   - epilogue in 4 slabs of 64 rows x 256 cols (ldsW stride 268 -> b128
//     reads spread across all 8 bank-quads).
// MODE-4 (W@V split-K) kernel unchanged. l1p slots 16 -> 8 per row.

typedef __bf16 bf16;
typedef bf16 bf16x4 __attribute__((ext_vector_type(4)));
typedef bf16 bf16x8 __attribute__((ext_vector_type(8)));
typedef float f32x4 __attribute__((ext_vector_type(4)));

#define S_DIM 2048
#define D_DIM 512
#define NB    4
#define EPSILON 0.01f

// ---------------- cast fp32 -> bf16 (vectorized x4) ----------------
__global__ void cast_kernel(const float* __restrict__ in, bf16* __restrict__ out, int n4) {
  int i = blockIdx.x * blockDim.x + threadIdx.x;
  if (i >= n4) return;
  float4 v = ((const float4*)in)[i];
  bf16x4 o = { (bf16)v.x, (bf16)v.y, (bf16)v.z, (bf16)v.w };
  ((bf16x4*)out)[i] = o;
}

// -- V preproc: V fp32 -> Vbf + Vt (bf16) + v2 row L2^2 (non-atomic) --
__global__ void vprep_kernel(const float* __restrict__ V, bf16* __restrict__ Vbf,
                             bf16* __restrict__ Vt, float* __restrict__ v2) {
  __shared__ float tile[64][68];
  int b  = blockIdx.y;
  int r0 = blockIdx.x * 64;
  const float* Vb = V   + (size_t)b * S_DIM * D_DIM;
  bf16*       Vfb = Vbf + (size_t)b * S_DIM * D_DIM;
  bf16*       Vtb = Vt  + (size_t)b * S_DIM * D_DIM;
  float*      v2b = v2  + (size_t)b * S_DIM;
  int tx = threadIdx.x & 15, ty = threadIdx.x >> 4;   // ty 0..15
  float acc2[4] = { 0.f, 0.f, 0.f, 0.f };
  for (int c = 0; c < 8; ++c) {
    int c0 = c * 64;
#pragma unroll
    for (int i = 0; i < 4; ++i) {
      int r = ty + i * 16;
      float4 v = *(const float4*)(Vb + (size_t)(r0 + r) * D_DIM + (c0 + tx * 4));
      tile[r][tx * 4 + 0] = v.x; tile[r][tx * 4 + 1] = v.y;
      tile[r][tx * 4 + 2] = v.z; tile[r][tx * 4 + 3] = v.w;
      bf16x4 o = { (bf16)v.x, (bf16)v.y, (bf16)v.z, (bf16)v.w };
      *(bf16x4*)(Vfb + (size_t)(r0 + r) * D_DIM + (c0 + tx * 4)) = o;
#pragma unroll
      for (int j = 0; j < 4; ++j) { float f = (float)o[j]; acc2[i] += f * f; }
    }
    __syncthreads();
#pragma unroll
    for (int i = 0; i < 4; ++i) {
      int cc = ty + i * 16;
      bf16x4 o = { (bf16)tile[tx * 4 + 0][cc], (bf16)tile[tx * 4 + 1][cc],
                   (bf16)tile[tx * 4 + 2][cc], (bf16)tile[tx * 4 + 3][cc] };
      *(bf16x4*)(Vtb + (size_t)(c0 + cc) * S_DIM + (r0 + tx * 4)) = o;
    }
    __syncthreads();   // tile reused next chunk
  }
#pragma unroll
  for (int i = 0; i < 4; ++i) {
    float s = acc2[i];
    s += __shfl_xor(s, 1); s += __shfl_xor(s, 2);
    s += __shfl_xor(s, 4); s += __shfl_xor(s, 8);
    if (tx == 0) v2b[r0 + ty + i * 16] = s;
  }
}

// ---------------- 256^2 pipelined NT GEMM + dist/weight epilogue ----------------
// C[M,N] tile 256x256, Amat (MxK), Bmat (NxK), K-tiles of 64, 8 waves (2Mx4N).
// Per-wave output 128x64 = acc[8][4] f32x4. LDS: 2 buf x (A 256x64 + B 256x64).
// Swizzle: 16B chunk p within a 128B row holds logical chunk p ^ (row&7).
__global__ __launch_bounds__(512, 2)
void gemm256_kernel(const bf16* __restrict__ Amat, const bf16* __restrict__ Bmat,
                    int M, int N, int K,
                    const float* __restrict__ m2, const float* __restrict__ v2,
                    const bf16* __restrict__ Aw, bf16* __restrict__ Wout,
                    float* __restrict__ l1p) {
  const int bz   = blockIdx.z;
  const int row0 = blockIdx.y * 256;
  const int col0 = blockIdx.x * 256;
  const bf16* Ab = Amat + (size_t)bz * M * K;
  const bf16* Bb = Bmat + (size_t)bz * N * K;

  __shared__ bf16 smem[65536];   // 128 KiB: [buf 64KB][ A 32KB | B 32KB ]

  const int tid  = threadIdx.x;
  const int w    = tid >> 6;     // wave 0..7
  const int lane = tid & 63;
  const int wr   = w >> 2;       // 0..1 -> 128-row half
  const int wc   = w & 3;        // 0..3 -> 64-col quarter
  const int q    = lane >> 4;
  const int c16  = lane & 15;
  const int srow = lane >> 3;            // 0..7 within the wave's 8 rows
  const int schk = (lane & 7) ^ srow;    // pre-swizzled source chunk

  f32x4 acc[8][4] = {};
  const int NT = K >> 6;

  auto stageA = [&](int nb, int k0) {
    bf16* la = smem + nb * 32768;
#pragma unroll
    for (int i = 0; i < 4; ++i)
      __builtin_amdgcn_global_load_lds(
          (const __attribute__((address_space(1))) void*)(
              Ab + (size_t)(row0 + i * 64 + w * 8 + srow) * K + (k0 + schk * 8)),
          (__attribute__((address_space(3))) void*)(la + (i * 64 + w * 8) * 64), 16, 0, 0);
  };
  auto stageB = [&](int nb, int k0) {
    bf16* lb = smem + nb * 32768 + 16384;
#pragma unroll
    for (int i = 0; i < 4; ++i)
      __builtin_amdgcn_global_load_lds(
          (const __attribute__((address_space(1))) void*)(
              Bb + (size_t)(col0 + i * 64 + w * 8 + srow) * K + (k0 + schk * 8)),
          (__attribute__((address_space(3))) void*)(lb + (i * 64 + w * 8) * 64), 16, 0, 0);
  };

  // prologue: tile 0 into buf 0
  stageA(0, 0); stageB(0, 0);
  asm volatile("s_waitcnt vmcnt(0)" ::: "memory");
  __builtin_amdgcn_s_barrier();

  int cur = 0;
  for (int t = 0; t < NT; ++t) {
    const int k0 = t << 6;
    const bf16* la = smem + cur * 32768;
    const bf16* lb = la + 16384;
    // issue next-tile A loads before compute (prefetch hides under MFMA)
    if (t + 1 < NT) stageA(cur ^ 1, k0 + 64);
#pragma unroll
    for (int kk = 0; kk < 2; ++kk) {
      bf16x8 afr[8], bfr[4];
      const int p = ((kk << 2) + q) ^ (c16 & 7);
#pragma unroll
      for (int m = 0; m < 8; ++m)
        afr[m] = *(const bf16x8*)(la + (size_t)(wr * 128 + m * 16 + c16) * 64 + p * 8);
#pragma unroll
      for (int n = 0; n < 4; ++n)
        bfr[n] = *(const bf16x8*)(lb + (size_t)(wc * 64 + n * 16 + c16) * 64 + p * 8);
      if (kk == 0 && t + 1 < NT) stageB(cur ^ 1, k0 + 64);
      __builtin_amdgcn_s_setprio(1);
#pragma unroll
      for (int m = 0; m < 8; ++m)
#pragma unroll
        for (int n = 0; n < 4; ++n)
          acc[m][n] = __builtin_amdgcn_mfma_f32_16x16x32_bf16(afr[m], bfr[n], acc[m][n], 0, 0, 0);
      __builtin_amdgcn_s_setprio(0);
    }
    // next tile must have landed; all waves done reading buf[cur]
    asm volatile("s_waitcnt vmcnt(0)" ::: "memory");
    __builtin_amdgcn_s_barrier();
    cur ^= 1;
  }

  // phase 1: w = rcp(sqrt(max(m2+v2-2P,0)) + eps), in place
  const float* m2b = m2 + (size_t)bz * M;
  const float* v2b = v2 + (size_t)bz * N;
  float v2v[4];
#pragma unroll
  for (int n = 0; n < 4; ++n) v2v[n] = v2b[col0 + wc * 64 + n * 16 + c16];
#pragma unroll
  for (int m = 0; m < 8; ++m)
#pragma unroll
    for (int r = 0; r < 4; ++r) {
      float m2v = m2b[row0 + wr * 128 + m * 16 + q * 4 + r];
#pragma unroll
      for (int n = 0; n < 4; ++n) {
        float d2 = fmaxf(m2v + v2v[n] - 2.f * acc[m][n][r], 0.f);
        acc[m][n][r] = __builtin_amdgcn_rcpf(__builtin_amdgcn_sqrtf(d2) + EPSILON);
      }
    }

  // phase 2: 4 slabs of 64 rows x 256 cols via LDS -> vectorized global I/O
  float* ldsW = (float*)smem;           // 64 x 268 fp32 = 68.6 KB
  const int lr  = tid >> 4;             // 0..31
  const int sub = tid & 15;             // 0..15  (16-col chunk)
#pragma unroll
  for (int s = 0; s < 4; ++s) {
    if (wr == (s >> 1)) {
      const int mb = (s & 1) * 4;
#pragma unroll
      for (int mt = 0; mt < 4; ++mt)
#pragma unroll
        for (int n = 0; n < 4; ++n)
#pragma unroll
          for (int r = 0; r < 4; ++r)
            ldsW[(mt * 16 + q * 4 + r) * 268 + wc * 64 + n * 16 + c16] = acc[mb + mt][n][r];
    }
    __syncthreads();
#pragma unroll
    for (int h2 = 0; h2 < 2; ++h2) {
      const int rloc = lr + 32 * h2;          // 0..63
      const int gi = row0 + s * 64 + rloc;
      const float* wp = ldsW + rloc * 268 + sub * 16;
      float4 w0 = *(const float4*)(wp + 0);
      float4 w1 = *(const float4*)(wp + 4);
      float4 w2 = *(const float4*)(wp + 8);
      float4 w3 = *(const float4*)(wp + 12);
      float wv_[16] = { w0.x, w0.y, w0.z, w0.w, w1.x, w1.y, w1.z, w1.w,
                        w2.x, w2.y, w2.z, w2.w, w3.x, w3.y, w3.z, w3.w };
      const bf16* ap = Aw + (size_t)bz * M * N + (size_t)gi * N + (col0 + sub * 16);
      bf16x8 a0 = *(const bf16x8*)(ap);
      bf16x8 a1 = *(const bf16x8*)(ap + 8);
      bf16x8 o0, o1;
      float rs = 0.f;
#pragma unroll
      for (int e = 0; e < 8; ++e) {
        float x0 = wv_[e] * (float)a0[e];
        float x1 = wv_[e + 8] * (float)a1[e];
        o0[e] = (bf16)x0; o1[e] = (bf16)x1;
        rs += fabsf(x0) + fabsf(x1);
      }
      bf16* op = Wout + (size_t)bz * M * N + (size_t)gi * N + (col0 + sub * 16);
      *(bf16x8*)(op)     = o0;
      *(bf16x8*)(op + 8) = o1;
      rs += __shfl_xor(rs, 1);
      rs += __shfl_xor(rs, 2);
      rs += __shfl_xor(rs, 4);
      rs += __shfl_xor(rs, 8);
      if (sub == 0) l1p[((size_t)blockIdx.x * NB + bz) * M + gi] = rs;
    }
    __syncthreads();
  }
}

// ---------------- NT GEMM 128^2 (MODE 4 only): split-K=2 bf16 partials ----------------
template <int MODE>
__global__ __launch_bounds__(256, 4)
void gemm_kernel(const bf16* __restrict__ Amat, const bf16* __restrict__ Bmat,
                 int M, int N, int K,
                 bf16* __restrict__ Cp,
                 const float* __restrict__ m2, const float* __restrict__ v2,
                 const bf16* __restrict__ Aw, bf16* __restrict__ Wout,
                 float* __restrict__ l1p) {
  int bz, ks, kbeg, kend;
  if (MODE == 4) { bz = blockIdx.z >> 1; ks = blockIdx.z & 1; kbeg = ks * (K >> 1); kend = kbeg + (K >> 1); }
  else           { bz = blockIdx.z;      ks = 0;              kbeg = 0;             kend = K; }
  const int row0 = blockIdx.y * 128;
  const int col0 = blockIdx.x * 128;
  const bf16* Ab = Amat + (size_t)bz * M * K;
  const bf16* Bb = Bmat + (size_t)bz * N * K;

  __shared__ char smem[33792];
  bf16*  ldsA = (bf16*)smem;
  bf16*  ldsB = (bf16*)(smem + 16384);
  float* ldsW = (float*)smem;

  const int tid  = threadIdx.x;
  const int wave = tid >> 6;
  const int lane = tid & 63;
  const int wr   = wave >> 1;
  const int wc   = wave & 1;
  const int q    = lane >> 4;
  const int c16  = lane & 15;

  const int srow = lane >> 3;
  const int scol = ((lane & 7) ^ srow) * 8;

  f32x4 acc[4][4] = {};

  for (int k0 = kbeg; k0 < kend; k0 += 64) {
#pragma unroll
    for (int i = 0; i < 4; ++i) {
      int slot = wave * 4 + i;
      int r = slot * 8 + srow;
      __builtin_amdgcn_global_load_lds(
          (const __attribute__((address_space(1))) void*)(Ab + (size_t)(row0 + r) * K + (k0 + scol)),
          (__attribute__((address_space(3))) void*)(ldsA + slot * 512), 16, 0, 0);
      __builtin_amdgcn_global_load_lds(
          (const __attribute__((address_space(1))) void*)(Bb + (size_t)(col0 + r) * K + (k0 + scol)),
          (__attribute__((address_space(3))) void*)(ldsB + slot * 512), 16, 0, 0);
    }
    __syncthreads();

#pragma unroll
    for (int kk = 0; kk < 2; ++kk) {
      bf16x8 afr[4], bfr[4];
#pragma unroll
      for (int mt = 0; mt < 4; ++mt) {
        int R = wr * 64 + mt * 16 + c16;
        int p = ((kk << 2) + q) ^ (c16 & 7);
        afr[mt] = *(const bf16x8*)(ldsA + (size_t)R * 64 + p * 8);
      }
#pragma unroll
      for (int nt = 0; nt < 4; ++nt) {
        int R = wc * 64 + nt * 16 + c16;
        int p = ((kk << 2) + q) ^ (c16 & 7);
        bfr[nt] = *(const bf16x8*)(ldsB + (size_t)R * 64 + p * 8);
      }
#pragma unroll
      for (int mt = 0; mt < 4; ++mt)
#pragma unroll
        for (int nt = 0; nt < 4; ++nt)
          acc[mt][nt] = __builtin_amdgcn_mfma_f32_16x16x32_bf16(afr[mt], bfr[nt], acc[mt][nt], 0, 0, 0);
    }
    __syncthreads();
  }

  const int lr  = tid >> 3;
  const int sub = tid & 7;
#pragma unroll
  for (int h = 0; h < 2; ++h) {
    __syncthreads();
    if (wr == h) {
#pragma unroll
      for (int mt = 0; mt < 4; ++mt)
#pragma unroll
        for (int nt = 0; nt < 4; ++nt)
#pragma unroll
          for (int r = 0; r < 4; ++r)
            ldsW[(mt * 16 + q * 4 + r) * 132 + wc * 64 + nt * 16 + c16] = acc[mt][nt][r];
    }
    __syncthreads();
#pragma unroll
    for (int h2 = 0; h2 < 2; ++h2) {
      int rloc = lr + 32 * h2;
      int gi = row0 + 64 * h + rloc;
      const float* wp = ldsW + rloc * 132 + sub * 16;
      float4 w0 = *(const float4*)(wp + 0);
      float4 w1 = *(const float4*)(wp + 4);
      float4 w2 = *(const float4*)(wp + 8);
      float4 w3 = *(const float4*)(wp + 12);
      float wv_[16] = { w0.x, w0.y, w0.z, w0.w, w1.x, w1.y, w1.z, w1.w,
                        w2.x, w2.y, w2.z, w2.w, w3.x, w3.y, w3.z, w3.w };
      bf16* Cb = Cp + ((size_t)ks * NB + bz) * ((size_t)M * N);
      bf16x8 o0, o1;
#pragma unroll
      for (int e = 0; e < 8; ++e) { o0[e] = (bf16)wv_[e]; o1[e] = (bf16)wv_[e + 8]; }
      bf16* op = Cb + (size_t)gi * N + (col0 + sub * 16);
      *(bf16x8*)(op)     = o0;
      *(bf16x8*)(op + 8) = o1;
    }
  }
}

// ---------------- reduce split-K=2 bf16 partials ----------------
// RMODE 0: Mbf + m2 ;  1: scale 1/l1 -> Mbf + m2 ;  2: scale 1/l1 -> fp32 out
__global__ void reduce_kernel_0(const bf16* __restrict__ part,
                                bf16* __restrict__ Mo, float* __restrict__ m2);
template <int RMODE>
__global__ void reduce_kernel(const bf16* __restrict__ part, const float* __restrict__ l1p,
                              bf16* __restrict__ Mo, float* __restrict__ Fo,
                              float* __restrict__ m2) {
  int wave = threadIdx.x >> 6, lane = threadIdx.x & 63;
  int rg = blockIdx.x * 4 + wave;          // 0..NB*S-1
  const bf16* p0 = part + (size_t)rg * D_DIM + lane * 8;
  const bf16* p1 = p0 + (size_t)NB * S_DIM * D_DIM;
  bf16x8 a = *(const bf16x8*)p0;
  bf16x8 b = *(const bf16x8*)p1;
  float v[8];
#pragma unroll
  for (int e = 0; e < 8; ++e) v[e] = (float)a[e] + (float)b[e];
  float sc = 1.f;
  if (RMODE >= 1) {
    int bb = rg >> 11, row = rg & (S_DIM - 1);
    float l1v = 0.f;
#pragma unroll
    for (int e = 0; e < 8; ++e) l1v += l1p[((size_t)e * NB + bb) * S_DIM + row];
    sc = __builtin_amdgcn_rcpf(fmaxf(l1v, 1e-12f));
  }
  float s = 0.f;
#pragma unroll
  for (int e = 0; e < 8; ++e) { v[e] *= sc; s += v[e] * v[e]; }
  if (RMODE == 2) {
    float4 o0 = { v[0], v[1], v[2], v[3] }, o1 = { v[4], v[5], v[6], v[7] };
    float* op = Fo + (size_t)rg * D_DIM + lane * 8;
    *(float4*)(op) = o0; *(float4*)(op + 4) = o1;
  } else {
    bf16x8 o;
#pragma unroll
    for (int e = 0; e < 8; ++e) o[e] = (bf16)v[e];
    *(bf16x8*)(Mo + (size_t)rg * D_DIM + lane * 8) = o;
#pragma unroll
    for (int off = 32; off > 0; off >>= 1) s += __shfl_xor(s, off);
    if (lane == 0) m2[rg] = s;
  }
}

extern "C" void kernel_launch(void* const* d_in, const int* in_sizes, int n_in,
                              void* d_out, int out_size, void* d_ws, size_t ws_size,
                              hipStream_t stream) {
  const float* A = (const float*)d_in[0];  // (4, 2048, 2048)
  const float* V = (const float*)d_in[1];  // (4, 2048, 512)
  float* out = (float*)d_out;              // (4, 2048, 512) fp32

  char* ws = (char*)d_ws;
  bf16* Abf = (bf16*)ws;   ws += (size_t)NB * S_DIM * S_DIM * 2;       // 33.5 MB
  bf16* Vbf = (bf16*)ws;   ws += (size_t)NB * S_DIM * D_DIM * 2;       //  8.4 MB
  bf16* Vt  = (bf16*)ws;   ws += (size_t)NB * S_DIM * D_DIM * 2;       //  8.4 MB
  bf16* Mbf = (bf16*)ws;   ws += (size_t)NB * S_DIM * D_DIM * 2;       //  8.4 MB
  bf16* Wbf = (bf16*)ws;   ws += (size_t)NB * S_DIM * S_DIM * 2;       // 33.5 MB
  bf16* part = (bf16*)ws;  ws += (size_t)2 * NB * S_DIM * D_DIM * 2;   // 16.8 MB
  float* v2 = (float*)ws;  ws += (size_t)NB * S_DIM * 4;
  float* m2 = (float*)ws;  ws += (size_t)NB * S_DIM * 4;
  float* l1p = (float*)ws; ws += (size_t)16 * NB * S_DIM * 4;          // 512 KB (8 used)

  int nA4 = NB * S_DIM * S_DIM / 4;
  cast_kernel<<<nA4 / 256, 256, 0, stream>>>(A, Abf, nA4);
  vprep_kernel<<<dim3(S_DIM / 64, NB), 256, 0, stream>>>(V, Vbf, Vt, v2);

  // M0 = A @ V  (split-K=2 bf16 partials -> reduce with m2)
  gemm_kernel<4><<<dim3(D_DIM / 128, S_DIM / 128, NB * 2), 256, 0, stream>>>(
      Abf, Vt, S_DIM, D_DIM, S_DIM, part, nullptr, nullptr, nullptr, nullptr, nullptr);
  reduce_kernel<0><<<NB * S_DIM / 4, 256, 0, stream>>>(part, nullptr, Mbf, nullptr, m2);

  for (int it = 0; it < 3; ++it) {
    // P = M @ V^T fused with dist/weight epilogue -> Wbf, l1p (256^2 pipelined)
    gemm256_kernel<<<dim3(S_DIM / 256, S_DIM / 256, NB), 512, 0, stream>>>(
        Mbf, Vbf, S_DIM, S_DIM, D_DIM, m2, v2, Abf, Wbf, l1p);
    // M = (W @ V) / l1  (split-K=2 bf16 partials -> reduce)
    gemm_kernel<4><<<dim3(D_DIM / 128, S_DIM / 128, NB * 2), 256, 0, stream>>>(
        Wbf, Vt, S_DIM, D_DIM, S_DIM, part, nullptr, nullptr, nullptr, nullptr, nullptr);
    if (it < 2)
      reduce_kernel<1><<<NB * S_DIM / 4, 256, 0, stream>>>(part, l1p, Mbf, nullptr, m2);
    else
      reduce_kernel<2><<<NB * S_DIM / 4, 256, 0, stream>>>(part, l1p, nullptr, out, nullptr);
  }
}